// Round 3
// baseline (215.129 us; speedup 1.0000x reference)
//
#include <hip/hip_runtime.h>
#include <math.h>

#define BB 4096
#define NN 8192
#define EPSF 1e-8f

// ws float layout:
// [0, BB)          : inv_rowsum  (1/(rowsum+eps)), written by rowsum_k
// [BB, BB+8)       : scalars: +0 conc, +1 conf, +2 rank, +3 nok   (atomic)
// [8192, 16384)    : final colsum (atomic or colreduce_k output)
// [16384, ...)     : per-block colsum partials (partial path only)
#define SCAL 4096
#define CS   8192
#define PP   16384

__global__ void init_ws(float* __restrict__ ws) {
    int i = blockIdx.x * blockDim.x + threadIdx.x;
    if (i < 12288) ws[SCAL + i] = 0.f;   // zero scalars + colsum
}

// wave-per-row rowsum: no LDS, no barriers
__global__ __launch_bounds__(256) void rowsum_k(const float* __restrict__ w,
                                                float* __restrict__ ws) {
    const int wave = threadIdx.x >> 6, lane = threadIdx.x & 63;
    const int row = blockIdx.x * 4 + wave;
    const float4* w4 = (const float4*)(w + (size_t)row * NN);
    float s = 0.f;
#pragma unroll
    for (int c = 0; c < 32; ++c) {
        float4 v = w4[c * 64 + lane];
        s += (v.x + v.y) + (v.z + v.w);
    }
#pragma unroll
    for (int off = 32; off; off >>= 1) s += __shfl_xor(s, off);
    if (lane == 0) ws[row] = 1.f / (s + EPSF);
}

template<int ROWS, int MODE>   // MODE 0: atomic colsum flush, 1: partial write
__global__ __launch_bounds__(512, 4) void main_k(
    const float* __restrict__ pr, const float* __restrict__ w,
    const float* __restrict__ cf, const float* __restrict__ ar,
    const float* __restrict__ mk, const float* __restrict__ sc,
    float* ws)
{
    const int t = threadIdx.x;
    const int wave = t >> 6, lane = t & 63;
    const int rowBase = blockIdx.x * ROWS;

    __shared__ float part[ROWS][8][8];   // [row][wave][7 values], pad to 8

    const float4* w4 = (const float4*)w;
    const float4* c4 = (const float4*)cf;
    const float4* a4 = (const float4*)ar;
    const float4* m4 = (const float4*)mk;
    const float4* s4 = (const float4*)sc;

    float invs[ROWS];
#pragma unroll
    for (int r = 0; r < ROWS; ++r) invs[r] = ws[rowBase + r];

    float csum[16];
#pragma unroll
    for (int j = 0; j < 16; ++j) csum[j] = 0.f;

    const size_t idx0 = (size_t)rowBase * (NN / 4) + t;

    // register double-buffer: cur group processed while next group's 5 loads in flight
    float4 nw, nm, nc, nr, ns;
    nw = w4[idx0]; nm = m4[idx0]; nc = c4[idx0]; nr = a4[idx0]; ns = s4[idx0];

    float conc = 0.f, scf = 0.f, tw = 0.f, nv = 0.f;
    float Zr = 0.f, A = 0.f, Zs = 0.f;
    // no max-subtraction needed: 20*ar in +-3, sc in +-6 -> exp safe in fp32

#pragma unroll
    for (int g = 0; g < 4 * ROWS; ++g) {
        const int rr = g >> 2, j = g & 3;
        const float4 bw = nw, bm = nm, bc = nc, br = nr, bs = ns;
        if (g + 1 < 4 * ROWS) {
            const size_t i = idx0 + (size_t)((g + 1) >> 2) * (NN / 4) + (size_t)((g + 1) & 3) * 512;
            nw = w4[i]; nm = m4[i]; nc = c4[i]; nr = a4[i]; ns = s4[i];
        }
        const float inv = invs[rr];

#define PROC(WK, MKV, CK, RK, SK, IDX) {                          \
        const float wk = (WK), mval = (MKV);                      \
        conc = fmaf(wk, __logf(wk + EPSF), conc);                 \
        const float wmk = wk * mval;                              \
        tw += wmk; scf = fmaf(wmk, (CK), scf);                    \
        nv += mval;                                               \
        const float er = __expf((RK) * 20.f) * mval;              \
        Zr += er; A = fmaf(er, (SK), A);                          \
        Zs = fmaf(__expf((SK)), mval, Zs);                        \
        csum[IDX] = fmaf(wmk, inv, csum[IDX]); }

        PROC(bw.x, bm.x, bc.x, br.x, bs.x, j * 4 + 0)
        PROC(bw.y, bm.y, bc.y, br.y, bs.y, j * 4 + 1)
        PROC(bw.z, bm.z, bc.z, br.z, bs.z, j * 4 + 2)
        PROC(bw.w, bm.w, bc.w, br.w, bs.w, j * 4 + 3)
#undef PROC

        if (j == 3) {
            // row complete: wave-level reduce 7 partials, park in LDS, reset
#pragma unroll
            for (int off = 32; off; off >>= 1) {
                conc += __shfl_xor(conc, off);
                scf  += __shfl_xor(scf, off);
                tw   += __shfl_xor(tw, off);
                nv   += __shfl_xor(nv, off);
                Zr   += __shfl_xor(Zr, off);
                A    += __shfl_xor(A, off);
                Zs   += __shfl_xor(Zs, off);
            }
            if (lane == 0) {
                float* p = part[rr][wave];
                p[0] = conc; p[1] = scf; p[2] = tw; p[3] = nv;
                p[4] = Zr;   p[5] = A;   p[6] = Zs;
            }
            conc = scf = tw = nv = Zr = A = Zs = 0.f;
        }
    }
    __syncthreads();   // the ONLY barrier in this kernel

    // per-row finalization in parallel: thread r handles row rowBase+r
    float c0 = 0.f, c1 = 0.f, c2 = 0.f, c3 = 0.f;
    if (t < ROWS) {
        float CO = 0, SC = 0, TW = 0, NV = 0, ZR = 0, AA = 0, ZS = 0;
        for (int k = 0; k < 8; ++k) {
            float* p = part[t][k];
            CO += p[0]; SC += p[1]; TW += p[2]; NV += p[3];
            ZR += p[4]; AA += p[5]; ZS += p[6];
        }
        c0 = CO;
        const float psc = SC / (TW + EPSF);
        const float ct = 1.f / (1.f + __expf(-50.f * pr[rowBase + t]));
        const float d = psc - ct;
        c1 = d * d;
        if (NV >= 2.f) {
            c2 = (__logf(ZS) - AA / ZR) / NV;   // per-sample ListNet loss
            c3 = 1.f;
        }
    }
    if (wave == 0) {
#pragma unroll
        for (int off = 32; off; off >>= 1) {
            c0 += __shfl_xor(c0, off);
            c1 += __shfl_xor(c1, off);
            c2 += __shfl_xor(c2, off);
            c3 += __shfl_xor(c3, off);
        }
        if (lane == 0) {
            atomicAdd(&ws[SCAL + 0], c0);
            atomicAdd(&ws[SCAL + 1], c1);
            atomicAdd(&ws[SCAL + 2], c2);
            atomicAdd(&ws[SCAL + 3], c3);
        }
    }

    // colsum flush
    if (MODE == 0) {
#pragma unroll
        for (int j = 0; j < 4; ++j) {
            const int f4 = t + j * 512;
            atomicAdd(&ws[CS + 4 * f4 + 0], csum[j * 4 + 0]);
            atomicAdd(&ws[CS + 4 * f4 + 1], csum[j * 4 + 1]);
            atomicAdd(&ws[CS + 4 * f4 + 2], csum[j * 4 + 2]);
            atomicAdd(&ws[CS + 4 * f4 + 3], csum[j * 4 + 3]);
        }
    } else {
        float4* dst = (float4*)(ws + PP) + (size_t)blockIdx.x * (NN / 4);
#pragma unroll
        for (int j = 0; j < 4; ++j) {
            const int f4 = t + j * 512;
            dst[f4] = make_float4(csum[j * 4 + 0], csum[j * 4 + 1],
                                  csum[j * 4 + 2], csum[j * 4 + 3]);
        }
    }
}

// reduce 1024 x NN partials -> colsum (partial path only). grid (32, 8)
__global__ __launch_bounds__(256) void colreduce_k(const float* __restrict__ src,
                                                   float* __restrict__ ws) {
    const int c = blockIdx.x * 256 + threadIdx.x;
    const int k0 = blockIdx.y * 128;
    float s = 0.f;
    for (int k = 0; k < 128; ++k) s += src[(size_t)(k0 + k) * NN + c];
    atomicAdd(&ws[CS + c], s);
}

__device__ __forceinline__ float block_sum_1024(float v) {
    __shared__ float scm[16];
#pragma unroll
    for (int off = 32; off; off >>= 1) v += __shfl_xor(v, off);
    if ((threadIdx.x & 63) == 0) scm[threadIdx.x >> 6] = v;
    __syncthreads();
    if (threadIdx.x == 0) {
        float a = 0.f;
        for (int k = 0; k < 16; ++k) a += scm[k];
        scm[0] = a;
    }
    __syncthreads();
    float r = scm[0];
    __syncthreads();
    return r;
}

__global__ __launch_bounds__(1024) void finalize(
    const float* __restrict__ pr, const float* __restrict__ ws,
    float* __restrict__ out)
{
    const int t = threadIdx.x;

    float s = 0.f, ssq = 0.f;
    for (int i = t; i < BB; i += 1024) { float v = pr[i]; s += v; ssq = fmaf(v, v, ssq); }
    float Tc = 0.f;
    for (int i = t; i < NN; i += 1024) Tc += ws[CS + i];

    float S  = block_sum_1024(s);
    float SS = block_sum_1024(ssq);
    float T  = block_sum_1024(Tc);

    const float mean = S / (float)BB;
    const float denom = T / (float)BB + EPSF;

    float ent = 0.f;
    for (int i = t; i < NN; i += 1024) {
        float a = ws[CS + i] / (float)BB;
        float na = a / denom;
        ent = fmaf(na, __logf(na + EPSF), ent);
    }
    float ENT = block_sum_1024(ent);  // = -batch_entropy = bent_loss

    if (t == 0) {
        float var = (SS - (float)BB * mean * mean) / (float)(BB - 1);
        float sd = sqrtf(fmaxf(var, 0.f));
        float sharpe = -mean / (sd + 0.01f);
        sharpe = fminf(fmaxf(sharpe, -10.f), 10.f);
        float conc_loss = -ws[SCAL + 0] / (float)BB;
        float conf_loss =  ws[SCAL + 1] / (float)BB;
        float nok = ws[SCAL + 3];
        float aux = (nok > 0.f) ? ws[SCAL + 2] / fmaxf(nok, 1.f) : 0.f;
        out[0] = 1.0f * (-mean)
               + 0.1f * sharpe
               + 0.01f * conc_loss
               + 0.1f * conf_loss
               + 0.01f * ENT
               + 0.1f * aux;
    }
}

extern "C" void kernel_launch(void* const* d_in, const int* in_sizes, int n_in,
                              void* d_out, int out_size, void* d_ws, size_t ws_size,
                              hipStream_t stream) {
    const float* pr = (const float*)d_in[0];
    const float* w  = (const float*)d_in[1];
    const float* cf = (const float*)d_in[2];
    const float* ar = (const float*)d_in[3];
    const float* mk = (const float*)d_in[4];
    const float* sc = (const float*)d_in[5];
    float* ws = (float*)d_ws;
    float* out = (float*)d_out;

    const size_t needBytes = ((size_t)PP + (size_t)1024 * NN) * sizeof(float);
    const bool partial = (ws_size >= needBytes);

    init_ws<<<(12288 + 255) / 256, 256, 0, stream>>>(ws);
    rowsum_k<<<1024, 256, 0, stream>>>(w, ws);
    if (partial) {
        main_k<4, 1><<<1024, 512, 0, stream>>>(pr, w, cf, ar, mk, sc, ws);
        colreduce_k<<<dim3(32, 8), 256, 0, stream>>>(ws + PP, ws);
    } else {
        main_k<8, 0><<<512, 512, 0, stream>>>(pr, w, cf, ar, mk, sc, ws);
    }
    finalize<<<1, 1024, 0, stream>>>(pr, ws, out);
}

// Round 4
// 184.443 us; speedup vs baseline: 1.1664x; 1.1664x over previous
//
#include <hip/hip_runtime.h>
#include <math.h>
#include <stdint.h>

#define BB 4096
#define NN 8192
#define EPSF 1e-8f

// ws float layout (same as validated R2):
// [0, 4096)        : inv_rowsum
// [4096, 4104)     : scalars: +0 conc, +1 conf, +2 rank, +3 nok (atomic)
// [8192, 16384)    : final colsum
// [16384, ...)     : per-block colsum partials (partial path)
#define SCAL 4096
#define CS   8192
#define PP   16384

__global__ void init_ws(float* __restrict__ ws) {
    int i = blockIdx.x * blockDim.x + threadIdx.x;
    if (i < 12288) ws[SCAL + i] = 0.f;   // zero scalars + colsum
}

// async global->LDS, 16B per lane, LDS dest = wave-uniform base + lane*16
__device__ __forceinline__ void dma16(const float* g, float* l) {
    __builtin_amdgcn_global_load_lds(
        (const __attribute__((address_space(1))) uint32_t*)(uintptr_t)g,
        (__attribute__((address_space(3))) uint32_t*)(uint32_t)(uintptr_t)l,
        16, 0, 0);
}

// wave-per-row rowsum: no LDS, no barriers
__global__ __launch_bounds__(256) void rowsum_k(const float* __restrict__ w,
                                                float* __restrict__ ws) {
    const int wave = threadIdx.x >> 6, lane = threadIdx.x & 63;
    const int row = blockIdx.x * 4 + wave;
    const float4* w4 = (const float4*)(w + (size_t)row * NN);
    float s = 0.f;
#pragma unroll
    for (int c = 0; c < 32; ++c) {
        float4 v = w4[c * 64 + lane];
        s += (v.x + v.y) + (v.z + v.w);
    }
#pragma unroll
    for (int off = 32; off; off >>= 1) s += __shfl_xor(s, off);
    if (lane == 0) ws[row] = 1.f / (s + EPSF);
}

// Each block: 4 waves; wave s handles column stripe [s*2048, (s+1)*2048) of
// rows [blockIdx*4, blockIdx*4+4). Wave-private LDS double-buffer fed by
// global_load_lds with counted vmcnt -- guaranteed MLP, no compiler sinking.
template<int MODE>   // 0: atomic colsum flush, 1: partial write
__global__ __launch_bounds__(256, 4) void main_k(
    const float* __restrict__ pr, const float* __restrict__ w,
    const float* __restrict__ cf, const float* __restrict__ ar,
    const float* __restrict__ mk, const float* __restrict__ sc,
    float* ws)
{
    __shared__ float lds[10240];      // 4 waves * (2 buf * 5 arr * 256 floats)
    __shared__ float park[4][4][8];   // [stripe][row][7 vals]

    const int t = threadIdx.x;
    const int s = t >> 6, lane = t & 63;
    const int rowBase = blockIdx.x * 4;
    float* wreg = lds + s * 2560;     // this wave's 10 KB region

    const int colBase = s * 2048 + lane * 4;
    const float* gw = w  + (size_t)rowBase * NN + colBase;
    const float* gm = mk + (size_t)rowBase * NN + colBase;
    const float* gc = cf + (size_t)rowBase * NN + colBase;
    const float* ga = ar + (size_t)rowBase * NN + colBase;
    const float* gq = sc + (size_t)rowBase * NN + colBase;

    float invs[4];
#pragma unroll
    for (int r = 0; r < 4; ++r) invs[r] = ws[rowBase + r];

    float csum[32];
#pragma unroll
    for (int j = 0; j < 32; ++j) csum[j] = 0.f;

    // prologue: stage group 0 (r=0,g=0) into buf0
    dma16(gw, wreg + 0);
    dma16(gm, wreg + 256);
    dma16(gc, wreg + 512);
    dma16(ga, wreg + 768);
    dma16(gq, wreg + 1024);

    float conc = 0.f, scf = 0.f, tw = 0.f, nv = 0.f;
    float Zr = 0.f, A = 0.f, Zs = 0.f;
    // no max-subtraction needed: 20*ar in +-3, sc in +-6 -> exp safe in fp32

#pragma unroll
    for (int it = 0; it < 32; ++it) {
        const int r = it >> 3, g = it & 7;
        if (it < 31) {
            const int it2 = it + 1;
            const size_t off = (size_t)(it2 >> 3) * NN + (size_t)(it2 & 7) * 256;
            float* b = wreg + (it2 & 1) * 1280;
            dma16(gw + off, b + 0);
            dma16(gm + off, b + 256);
            dma16(gc + off, b + 512);
            dma16(ga + off, b + 768);
            dma16(gq + off, b + 1024);
            // all but the 5 newest (the prefetch just issued) must be done:
            // guarantees group `it`'s DMAs have landed. Strays only over-wait.
            asm volatile("s_waitcnt vmcnt(5)" ::: "memory");
        } else {
            asm volatile("s_waitcnt vmcnt(0)" ::: "memory");
        }
        const float* b = wreg + (it & 1) * 1280;
        const float4 bw = *(const float4*)(b + 0    + lane * 4);
        const float4 bm = *(const float4*)(b + 256  + lane * 4);
        const float4 bc = *(const float4*)(b + 512  + lane * 4);
        const float4 br = *(const float4*)(b + 768  + lane * 4);
        const float4 bs = *(const float4*)(b + 1024 + lane * 4);
        const float inv = invs[r];

#define PROC(WK, MKV, CK, RK, SK, IDX) {                          \
        const float wk = (WK), mval = (MKV);                      \
        conc = fmaf(wk, __logf(wk + EPSF), conc);                 \
        const float wmk = wk * mval;                              \
        tw += wmk; scf = fmaf(wmk, (CK), scf);                    \
        nv += mval;                                               \
        const float er = __expf((RK) * 20.f) * mval;              \
        Zr += er; A = fmaf(er, (SK), A);                          \
        Zs = fmaf(__expf((SK)), mval, Zs);                        \
        csum[IDX] = fmaf(wmk, inv, csum[IDX]); }

        PROC(bw.x, bm.x, bc.x, br.x, bs.x, g * 4 + 0)
        PROC(bw.y, bm.y, bc.y, br.y, bs.y, g * 4 + 1)
        PROC(bw.z, bm.z, bc.z, br.z, bs.z, g * 4 + 2)
        PROC(bw.w, bm.w, bc.w, br.w, bs.w, g * 4 + 3)
#undef PROC

        if (g == 7) {   // row complete: wave-reduce 7 partials, park, reset
#pragma unroll
            for (int off = 32; off; off >>= 1) {
                conc += __shfl_xor(conc, off);
                scf  += __shfl_xor(scf, off);
                tw   += __shfl_xor(tw, off);
                nv   += __shfl_xor(nv, off);
                Zr   += __shfl_xor(Zr, off);
                A    += __shfl_xor(A, off);
                Zs   += __shfl_xor(Zs, off);
            }
            if (lane == 0) {
                float* p = park[s][r];
                p[0] = conc; p[1] = scf; p[2] = tw; p[3] = nv;
                p[4] = Zr;   p[5] = A;   p[6] = Zs;
            }
            conc = scf = tw = nv = Zr = A = Zs = 0.f;
        }
    }

    // colsum flush (per-wave 2048-col stripe, summed over this block's 4 rows)
    if (MODE == 1) {
        float* dst = ws + PP + (size_t)blockIdx.x * NN + colBase;
#pragma unroll
        for (int g = 0; g < 8; ++g)
            *(float4*)(dst + g * 256) = make_float4(csum[g * 4 + 0], csum[g * 4 + 1],
                                                    csum[g * 4 + 2], csum[g * 4 + 3]);
    } else {
#pragma unroll
        for (int g = 0; g < 8; ++g) {
            atomicAdd(&ws[CS + colBase + g * 256 + 0], csum[g * 4 + 0]);
            atomicAdd(&ws[CS + colBase + g * 256 + 1], csum[g * 4 + 1]);
            atomicAdd(&ws[CS + colBase + g * 256 + 2], csum[g * 4 + 2]);
            atomicAdd(&ws[CS + colBase + g * 256 + 3], csum[g * 4 + 3]);
        }
    }

    __syncthreads();   // the ONLY barrier: park slots now visible

    if (t < 64) {      // wave 0: lanes 0..3 finalize the block's 4 rows
        float c0 = 0.f, c1 = 0.f, c2 = 0.f, c3 = 0.f;
        if (lane < 4) {
            float CO = 0, SC = 0, TW = 0, NV = 0, ZR = 0, AA = 0, ZS = 0;
#pragma unroll
            for (int ss = 0; ss < 4; ++ss) {
                const float* p = park[ss][lane];
                CO += p[0]; SC += p[1]; TW += p[2]; NV += p[3];
                ZR += p[4]; AA += p[5]; ZS += p[6];
            }
            c0 = CO;
            const float psc = SC / (TW + EPSF);
            const float ct = 1.f / (1.f + __expf(-50.f * pr[rowBase + lane]));
            const float d = psc - ct;
            c1 = d * d;
            if (NV >= 2.f) {
                c2 = (__logf(ZS) - AA / ZR) / NV;   // per-sample ListNet loss
                c3 = 1.f;
            }
        }
        c0 += __shfl_xor(c0, 1); c0 += __shfl_xor(c0, 2);
        c1 += __shfl_xor(c1, 1); c1 += __shfl_xor(c1, 2);
        c2 += __shfl_xor(c2, 1); c2 += __shfl_xor(c2, 2);
        c3 += __shfl_xor(c3, 1); c3 += __shfl_xor(c3, 2);
        if (lane == 0) {
            atomicAdd(&ws[SCAL + 0], c0);
            atomicAdd(&ws[SCAL + 1], c1);
            atomicAdd(&ws[SCAL + 2], c2);
            atomicAdd(&ws[SCAL + 3], c3);
        }
    }
}

// reduce 1024 x NN partials -> colsum (partial path only). grid (32, 8)
__global__ __launch_bounds__(256) void colreduce_k(const float* __restrict__ src,
                                                   float* __restrict__ ws) {
    const int c = blockIdx.x * 256 + threadIdx.x;
    const int k0 = blockIdx.y * 128;
    float s = 0.f;
    for (int k = 0; k < 128; ++k) s += src[(size_t)(k0 + k) * NN + c];
    atomicAdd(&ws[CS + c], s);
}

__device__ __forceinline__ float block_sum_1024(float v) {
    __shared__ float scm[16];
#pragma unroll
    for (int off = 32; off; off >>= 1) v += __shfl_xor(v, off);
    if ((threadIdx.x & 63) == 0) scm[threadIdx.x >> 6] = v;
    __syncthreads();
    if (threadIdx.x == 0) {
        float a = 0.f;
        for (int k = 0; k < 16; ++k) a += scm[k];
        scm[0] = a;
    }
    __syncthreads();
    float r = scm[0];
    __syncthreads();
    return r;
}

__global__ __launch_bounds__(1024) void finalize(
    const float* __restrict__ pr, const float* __restrict__ ws,
    float* __restrict__ out)
{
    const int t = threadIdx.x;

    float s = 0.f, ssq = 0.f;
    for (int i = t; i < BB; i += 1024) { float v = pr[i]; s += v; ssq = fmaf(v, v, ssq); }
    float Tc = 0.f;
    for (int i = t; i < NN; i += 1024) Tc += ws[CS + i];

    float S  = block_sum_1024(s);
    float SS = block_sum_1024(ssq);
    float T  = block_sum_1024(Tc);

    const float mean = S / (float)BB;
    const float denom = T / (float)BB + EPSF;

    float ent = 0.f;
    for (int i = t; i < NN; i += 1024) {
        float a = ws[CS + i] / (float)BB;
        float na = a / denom;
        ent = fmaf(na, __logf(na + EPSF), ent);
    }
    float ENT = block_sum_1024(ent);  // = -batch_entropy = bent_loss

    if (t == 0) {
        float var = (SS - (float)BB * mean * mean) / (float)(BB - 1);
        float sd = sqrtf(fmaxf(var, 0.f));
        float sharpe = -mean / (sd + 0.01f);
        sharpe = fminf(fmaxf(sharpe, -10.f), 10.f);
        float conc_loss = -ws[SCAL + 0] / (float)BB;
        float conf_loss =  ws[SCAL + 1] / (float)BB;
        float nok = ws[SCAL + 3];
        float aux = (nok > 0.f) ? ws[SCAL + 2] / fmaxf(nok, 1.f) : 0.f;
        out[0] = 1.0f * (-mean)
               + 0.1f * sharpe
               + 0.01f * conc_loss
               + 0.1f * conf_loss
               + 0.01f * ENT
               + 0.1f * aux;
    }
}

extern "C" void kernel_launch(void* const* d_in, const int* in_sizes, int n_in,
                              void* d_out, int out_size, void* d_ws, size_t ws_size,
                              hipStream_t stream) {
    const float* pr = (const float*)d_in[0];
    const float* w  = (const float*)d_in[1];
    const float* cf = (const float*)d_in[2];
    const float* ar = (const float*)d_in[3];
    const float* mk = (const float*)d_in[4];
    const float* sc = (const float*)d_in[5];
    float* ws = (float*)d_ws;
    float* out = (float*)d_out;

    const size_t needBytes = ((size_t)PP + (size_t)1024 * NN) * sizeof(float);
    const bool partial = (ws_size >= needBytes);

    init_ws<<<48, 256, 0, stream>>>(ws);
    rowsum_k<<<1024, 256, 0, stream>>>(w, ws);
    if (partial) {
        main_k<1><<<1024, 256, 0, stream>>>(pr, w, cf, ar, mk, sc, ws);
        colreduce_k<<<dim3(32, 8), 256, 0, stream>>>(ws + PP, ws);
    } else {
        main_k<0><<<1024, 256, 0, stream>>>(pr, w, cf, ar, mk, sc, ws);
    }
    finalize<<<1, 1024, 0, stream>>>(pr, ws, out);
}

// Round 7
// 169.230 us; speedup vs baseline: 1.2712x; 1.0899x over previous
//
#include <hip/hip_runtime.h>
#include <math.h>

#define BB 4096
#define NN 8192
#define EPSF 1e-8f

typedef float f32x4 __attribute__((ext_vector_type(4)));

// ws float layout:
// [0, BB)          : inv_rowsum  (1/(rowsum+eps)), written by rowsum_k
// [BB, BB+8)       : scalars: +0 conc, +1 conf, +2 rank, +3 nok   (atomic)
// [8192, 16384)    : final colsum (atomic or colreduce_k output)
// [16384, ...)     : per-block colsum partials (partial path only)
#define SCAL 4096
#define CS   8192
#define PP   16384

__global__ void init_ws(float* __restrict__ ws) {
    int i = blockIdx.x * blockDim.x + threadIdx.x;
    if (i < 12288) ws[SCAL + i] = 0.f;   // zero scalars + colsum
}

// wave-per-row rowsum: no LDS, no barriers. Cached loads -> warms L3 with w.
__global__ __launch_bounds__(256) void rowsum_k(const float* __restrict__ w,
                                                float* __restrict__ ws) {
    const int wave = threadIdx.x >> 6, lane = threadIdx.x & 63;
    const int row = blockIdx.x * 4 + wave;
    const f32x4* w4 = (const f32x4*)(w + (size_t)row * NN);
    float s = 0.f;
#pragma unroll
    for (int c = 0; c < 32; ++c) {
        f32x4 v = w4[c * 64 + lane];
        s += (v.x + v.y) + (v.z + v.w);
    }
#pragma unroll
    for (int off = 32; off; off >>= 1) s += __shfl_xor(s, off);
    if (lane == 0) ws[row] = 1.f / (s + EPSF);
}

template<int ROWS, int MODE>   // MODE 0: atomic colsum flush, 1: partial write
__global__ __launch_bounds__(512) void main_k(
    const float* __restrict__ pr, const float* __restrict__ w,
    const float* __restrict__ cf, const float* __restrict__ ar,
    const float* __restrict__ mk, const float* __restrict__ sc,
    float* ws)
{
    const int t = threadIdx.x;
    const int wave = t >> 6, lane = t & 63;
    const int rowBase = blockIdx.x * ROWS;

    __shared__ float part[ROWS][8][8];   // [row][wave][7 values], pad to 8

    float csum[16];
#pragma unroll
    for (int j = 0; j < 16; ++j) csum[j] = 0.f;

    for (int rr = 0; rr < ROWS; ++rr) {
        const int row = rowBase + rr;
        const size_t base = (size_t)row * NN;
        const float inv = ws[row];                 // uniform -> scalar load
        const f32x4* w4 = (const f32x4*)(w + base);   // cached: L3-resident
        const f32x4* c4 = (const f32x4*)(cf + base);  // NT below: zero reuse
        const f32x4* a4 = (const f32x4*)(ar + base);
        const f32x4* m4 = (const f32x4*)(mk + base);
        const f32x4* s4 = (const f32x4*)(sc + base);

        float conc = 0.f, scf = 0.f, tw = 0.f, nv = 0.f;
        float Zr = 0.f, A = 0.f, Zs = 0.f;   // no max-subtraction needed:
                                             // 20*ar in +-3, sc in +-6 -> exp safe in fp32
#define PROC(WK, MKV, CK, RK, SK, IDX) {                          \
        const float wk = (WK), mval = (MKV);                      \
        conc = fmaf(wk, __logf(wk + EPSF), conc);                 \
        const float wmk = wk * mval;                              \
        tw += wmk; scf = fmaf(wmk, (CK), scf);                    \
        nv += mval;                                               \
        const float er = __expf((RK) * 20.f) * mval;              \
        Zr += er; A = fmaf(er, (SK), A);                          \
        Zs = fmaf(__expf((SK)), mval, Zs);                        \
        csum[IDX] = fmaf(wmk, inv, csum[IDX]); }

#pragma unroll
        for (int j = 0; j < 4; ++j) {
            const int f4 = t + j * 512;
            f32x4 wv = w4[f4];
            f32x4 mv = __builtin_nontemporal_load(m4 + f4);
            f32x4 cv = __builtin_nontemporal_load(c4 + f4);
            f32x4 rv = __builtin_nontemporal_load(a4 + f4);
            f32x4 sv = __builtin_nontemporal_load(s4 + f4);
            PROC(wv.x, mv.x, cv.x, rv.x, sv.x, j * 4 + 0)
            PROC(wv.y, mv.y, cv.y, rv.y, sv.y, j * 4 + 1)
            PROC(wv.z, mv.z, cv.z, rv.z, sv.z, j * 4 + 2)
            PROC(wv.w, mv.w, cv.w, rv.w, sv.w, j * 4 + 3)
        }
#undef PROC

        // wave-level reduction of the 7 per-row partials (no block barrier)
#pragma unroll
        for (int off = 32; off; off >>= 1) {
            conc += __shfl_xor(conc, off);
            scf  += __shfl_xor(scf, off);
            tw   += __shfl_xor(tw, off);
            nv   += __shfl_xor(nv, off);
            Zr   += __shfl_xor(Zr, off);
            A    += __shfl_xor(A, off);
            Zs   += __shfl_xor(Zs, off);
        }
        if (lane == 0) {
            float* p = part[rr][wave];
            p[0] = conc; p[1] = scf; p[2] = tw; p[3] = nv;
            p[4] = Zr;   p[5] = A;   p[6] = Zs;
        }
    }
    __syncthreads();   // the ONLY barrier in this kernel

    // per-row finalization in parallel: thread r handles row rowBase+r
    float c0 = 0.f, c1 = 0.f, c2 = 0.f, c3 = 0.f;
    if (t < ROWS) {
        float CO = 0, SC = 0, TW = 0, NV = 0, ZR = 0, AA = 0, ZS = 0;
        for (int k = 0; k < 8; ++k) {
            float* p = part[t][k];
            CO += p[0]; SC += p[1]; TW += p[2]; NV += p[3];
            ZR += p[4]; AA += p[5]; ZS += p[6];
        }
        c0 = CO;
        const float psc = SC / (TW + EPSF);
        const float ct = 1.f / (1.f + __expf(-50.f * pr[rowBase + t]));
        const float d = psc - ct;
        c1 = d * d;
        if (NV >= 2.f) {
            c2 = (__logf(ZS) - AA / ZR) / NV;   // per-sample ListNet loss
            c3 = 1.f;
        }
    }
    if (wave == 0) {
#pragma unroll
        for (int off = 32; off; off >>= 1) {
            c0 += __shfl_xor(c0, off);
            c1 += __shfl_xor(c1, off);
            c2 += __shfl_xor(c2, off);
            c3 += __shfl_xor(c3, off);
        }
        if (lane == 0) {
            atomicAdd(&ws[SCAL + 0], c0);
            atomicAdd(&ws[SCAL + 1], c1);
            atomicAdd(&ws[SCAL + 2], c2);
            atomicAdd(&ws[SCAL + 3], c3);
        }
    }

    // colsum flush
    if (MODE == 0) {
#pragma unroll
        for (int j = 0; j < 4; ++j) {
            const int f4 = t + j * 512;
            atomicAdd(&ws[CS + 4 * f4 + 0], csum[j * 4 + 0]);
            atomicAdd(&ws[CS + 4 * f4 + 1], csum[j * 4 + 1]);
            atomicAdd(&ws[CS + 4 * f4 + 2], csum[j * 4 + 2]);
            atomicAdd(&ws[CS + 4 * f4 + 3], csum[j * 4 + 3]);
        }
    } else {
        f32x4* dst = (f32x4*)(ws + PP) + (size_t)blockIdx.x * (NN / 4);
#pragma unroll
        for (int j = 0; j < 4; ++j) {
            const int f4 = t + j * 512;
            f32x4 v;
            v.x = csum[j * 4 + 0]; v.y = csum[j * 4 + 1];
            v.z = csum[j * 4 + 2]; v.w = csum[j * 4 + 3];
            __builtin_nontemporal_store(v, dst + f4);
        }
    }
}

// reduce 1024 x NN partials -> colsum (partial path only). grid (32, 8)
__global__ __launch_bounds__(256) void colreduce_k(const float* __restrict__ src,
                                                   float* __restrict__ ws) {
    const int c = blockIdx.x * 256 + threadIdx.x;
    const int k0 = blockIdx.y * 128;
    float s = 0.f;
    for (int k = 0; k < 128; ++k) s += src[(size_t)(k0 + k) * NN + c];
    atomicAdd(&ws[CS + c], s);
}

__device__ __forceinline__ float block_sum_1024(float v) {
    __shared__ float scm[16];
#pragma unroll
    for (int off = 32; off; off >>= 1) v += __shfl_xor(v, off);
    if ((threadIdx.x & 63) == 0) scm[threadIdx.x >> 6] = v;
    __syncthreads();
    if (threadIdx.x == 0) {
        float a = 0.f;
        for (int k = 0; k < 16; ++k) a += scm[k];
        scm[0] = a;
    }
    __syncthreads();
    float r = scm[0];
    __syncthreads();
    return r;
}

__global__ __launch_bounds__(1024) void finalize(
    const float* __restrict__ pr, const float* __restrict__ ws,
    float* __restrict__ out)
{
    const int t = threadIdx.x;

    float s = 0.f, ssq = 0.f;
    for (int i = t; i < BB; i += 1024) { float v = pr[i]; s += v; ssq = fmaf(v, v, ssq); }
    float Tc = 0.f;
    for (int i = t; i < NN; i += 1024) Tc += ws[CS + i];

    float S  = block_sum_1024(s);
    float SS = block_sum_1024(ssq);
    float T  = block_sum_1024(Tc);

    const float mean = S / (float)BB;
    const float denom = T / (float)BB + EPSF;

    float ent = 0.f;
    for (int i = t; i < NN; i += 1024) {
        float a = ws[CS + i] / (float)BB;
        float na = a / denom;
        ent = fmaf(na, __logf(na + EPSF), ent);
    }
    float ENT = block_sum_1024(ent);  // = -batch_entropy = bent_loss

    if (t == 0) {
        float var = (SS - (float)BB * mean * mean) / (float)(BB - 1);
        float sd = sqrtf(fmaxf(var, 0.f));
        float sharpe = -mean / (sd + 0.01f);
        sharpe = fminf(fmaxf(sharpe, -10.f), 10.f);
        float conc_loss = -ws[SCAL + 0] / (float)BB;
        float conf_loss =  ws[SCAL + 1] / (float)BB;
        float nok = ws[SCAL + 3];
        float aux = (nok > 0.f) ? ws[SCAL + 2] / fmaxf(nok, 1.f) : 0.f;
        out[0] = 1.0f * (-mean)
               + 0.1f * sharpe
               + 0.01f * conc_loss
               + 0.1f * conf_loss
               + 0.01f * ENT
               + 0.1f * aux;
    }
}

extern "C" void kernel_launch(void* const* d_in, const int* in_sizes, int n_in,
                              void* d_out, int out_size, void* d_ws, size_t ws_size,
                              hipStream_t stream) {
    const float* pr = (const float*)d_in[0];
    const float* w  = (const float*)d_in[1];
    const float* cf = (const float*)d_in[2];
    const float* ar = (const float*)d_in[3];
    const float* mk = (const float*)d_in[4];
    const float* sc = (const float*)d_in[5];
    float* ws = (float*)d_ws;
    float* out = (float*)d_out;

    const size_t needBytes = ((size_t)PP + (size_t)1024 * NN) * sizeof(float);
    const bool partial = (ws_size >= needBytes);

    init_ws<<<48, 256, 0, stream>>>(ws);
    rowsum_k<<<1024, 256, 0, stream>>>(w, ws);
    if (partial) {
        main_k<4, 1><<<1024, 512, 0, stream>>>(pr, w, cf, ar, mk, sc, ws);
        colreduce_k<<<dim3(32, 8), 256, 0, stream>>>(ws + PP, ws);
    } else {
        main_k<8, 0><<<512, 512, 0, stream>>>(pr, w, cf, ar, mk, sc, ws);
    }
    finalize<<<1, 1024, 0, stream>>>(pr, ws, out);
}